// Round 1
// baseline (885.703 us; speedup 1.0000x reference)
//
#include <hip/hip_runtime.h>

#define HP   768      // padded H
#define WP   768      // padded W
#define NV   385      // WP/2 + 1
#define HIN  512
#define WIN  512
#define PAD  128      // HIN/4
#define K    8        // truncation radius of spatial inverse kernel
#define A    17       // 2K+1
#define TW   64       // output tile width per block
#define TH   16       // output tile height per block
#define LW   (TW + 2*K)   // 80
#define LH   (TH + 2*K)   // 32

#define TWO_PI_OVER_HP 0.008181230868723419f  // 2*pi/768

__device__ inline float2 cmul(float2 a, float2 b) {
    return make_float2(a.x*b.x - a.y*b.y, a.x*b.y + a.y*b.x);
}

// F(u,v) = sum_{i<3,j<3} w[i,j] * exp(-2*pi*i*(u*i + v*j)/768)
__device__ inline float2 evalF(int u, int v, const float* w9) {
    float fr = 0.f, fi = 0.f;
#pragma unroll
    for (int i = 0; i < 3; ++i) {
#pragma unroll
        for (int j = 0; j < 3; ++j) {
            int p = (u * i + v * j) % HP;
            float ang = (float)p * TWO_PI_OVER_HP;
            float s, c;
            sincosf(ang, &s, &c);
            float wv = w9[i * 3 + j];
            fr += wv * c;
            fi -= wv * s;
        }
    }
    return make_float2(fr, fi);
}

// One block per rfft column v. Builds gmf[.,v] in LDS, then
// P[a,v] = sum_u gmf[u,v] * exp(+2*pi*i*u*a'/768)  for a' in [-K,K].
__global__ __launch_bounds__(256) void filt_P_kernel(
        const float* __restrict__ w, float2* __restrict__ P) {
    __shared__ float2 lg[HP];
    int v = blockIdx.x;
    int tid = threadIdx.x;

    float w9[9];
#pragma unroll
    for (int i = 0; i < 9; ++i) w9[i] = w[i];

    int sv = (v == 0) ? 0 : (NV - v);   // reference's reverse+roll index
    for (int u = tid; u < HP; u += 256) {
        int su = (HP - u) % HP;
        float2 F1 = evalF(u,  v,  w9);
        float2 F2 = evalF(su, v,  w9);
        float2 F3 = evalF(u,  sv, w9);
        float2 F4 = evalF(su, sv, w9);
        float2 pr = cmul(cmul(F1, F2), cmul(F3, F4));
        float d = pr.x * pr.x + pr.y * pr.y;
        lg[u] = make_float2(pr.x / d, -pr.y / d);   // 1/prod
    }
    __syncthreads();

    if (tid < A) {
        int ap = tid - K;
        float Pr = 0.f, Pi = 0.f;
        for (int u = 0; u < HP; ++u) {
            int m = (u * ap) % HP;
            if (m < 0) m += HP;
            float ang = (float)m * TWO_PI_OVER_HP;
            float s, c;
            sincosf(ang, &s, &c);
            float2 g = lg[u];
            Pr += g.x * c - g.y * s;
            Pi += g.x * s + g.y * c;
        }
        P[tid * NV + v] = make_float2(Pr, Pi);
    }
}

// g[a,b] = (1/768^2) * sum_v w_v * Re(P[a,v] * exp(+2*pi*i*v*b'/768))
__global__ __launch_bounds__(256) void filt_gk_kernel(
        const float2* __restrict__ P, float* __restrict__ gk) {
    int id = blockIdx.x * 256 + threadIdx.x;
    if (id >= A * A) return;
    int ai = id / A;
    int bi = id - ai * A;
    int bp = bi - K;
    float sum = 0.f;
    for (int v = 0; v < NV; ++v) {
        float wv = (v == 0 || v == NV - 1) ? 1.f : 2.f;
        int m = (v * bp) % HP;
        if (m < 0) m += HP;
        float ang = (float)m * TWO_PI_OVER_HP;
        float s, c;
        sincosf(ang, &s, &c);
        float2 p = P[ai * NV + v];
        sum += wv * (p.x * c - p.y * s);
    }
    gk[id] = sum * (1.f / ((float)HP * (float)WP));
}

// Direct 17x17 convolution of zero-padded x into the 768x768 output grid.
// ym[oy,ox] = sum_{a',b' in [-K,K]} g[a',b'] * X(oy-128-a', ox-128-b')
__global__ __launch_bounds__(256) void deconv_kernel(
        const float* __restrict__ x, const float* __restrict__ gk,
        float* __restrict__ out) {
    __shared__ __align__(16) float tile[LH * LW];
    int tx = threadIdx.x;   // 0..15
    int ty = threadIdx.y;   // 0..15
    int bx = blockIdx.x;    // 0..11
    int by = blockIdx.y;    // 0..47
    int bz = blockIdx.z;    // batch

    int ix0 = bx * TW - PAD - K;
    int iy0 = by * TH - PAD - K;
    int oy  = by * TH + ty;
    int ox0 = bx * TW + tx * 4;
    float4* outp = (float4*)(out + ((size_t)bz * HP + oy) * WP + ox0);

    bool active = (iy0 <= HIN - 1) && (iy0 + LH - 1 >= 0) &&
                  (ix0 <= WIN - 1) && (ix0 + LW - 1 >= 0);
    if (!active) {
        *outp = make_float4(0.f, 0.f, 0.f, 0.f);
        return;
    }

    const float* xb = x + (size_t)bz * HIN * WIN;
    int tid = ty * 16 + tx;
    for (int l = tid; l < LH * LW; l += 256) {
        int r = l / LW;
        int c = l - r * LW;
        int gy = iy0 + r;
        int gx = ix0 + c;
        float v = 0.f;
        if ((unsigned)gy < (unsigned)HIN && (unsigned)gx < (unsigned)WIN)
            v = xb[gy * WIN + gx];
        tile[l] = v;
    }
    __syncthreads();

    float acc0 = 0.f, acc1 = 0.f, acc2 = 0.f, acc3 = 0.f;
#pragma unroll
    for (int aa = 0; aa < A; ++aa) {
        float rb[20];
#pragma unroll
        for (int k4 = 0; k4 < 5; ++k4)
            *(float4*)&rb[k4 * 4] =
                *(const float4*)&tile[(ty + aa) * LW + tx * 4 + k4 * 4];
#pragma unroll
        for (int bb = 0; bb < A; ++bb) {
            // flipped taps: conv index a' = K - aa, b' = K - bb
            float gv = gk[(2 * K - aa) * A + (2 * K - bb)];
            acc0 += gv * rb[bb];
            acc1 += gv * rb[bb + 1];
            acc2 += gv * rb[bb + 2];
            acc3 += gv * rb[bb + 3];
        }
    }
    *outp = make_float4(acc0, acc1, acc2, acc3);
}

extern "C" void kernel_launch(void* const* d_in, const int* in_sizes, int n_in,
                              void* d_out, int out_size, void* d_ws, size_t ws_size,
                              hipStream_t stream) {
    const float* x = (const float*)d_in[0];   // (64, 512, 512) fp32
    const float* w = (const float*)d_in[1];   // (3, 3) fp32
    float* out = (float*)d_out;               // (64, 768, 768) fp32

    // workspace layout (floats): P = A*NV float2, then gk = A*A floats
    float2* P  = (float2*)d_ws;
    float*  gk = (float*)d_ws + (size_t)A * NV * 2;

    filt_P_kernel<<<dim3(NV), dim3(256), 0, stream>>>(w, P);
    filt_gk_kernel<<<dim3((A * A + 255) / 256), dim3(256), 0, stream>>>(P, gk);
    deconv_kernel<<<dim3(WP / TW, HP / TH, 64), dim3(16, 16), 0, stream>>>(x, gk, out);
}

// Round 2
// 496.140 us; speedup vs baseline: 1.7852x; 1.7852x over previous
//
#include <hip/hip_runtime.h>

#define HP   768      // padded H (=W)
#define NV   385      // HP/2 + 1
#define HIN  512
#define WIN  512
#define K    8        // truncation radius of spatial inverse kernel
#define A    17       // 2K+1
#define PADO 136      // PAD + K = 128 + 8
#define TW   64       // output tile width
#define TH   32       // output tile height
#define LH   48       // TH + 2K
#define LWL  80       // TW + 2K (logical tile width)
#define LWS  84       // padded LDS stride (breaks bank aliasing)
#define GKS  20       // gk LDS row stride (padded from 17)

#define TWO_PI_OVER_HP 0.008181230868723419f  // 2*pi/768

__device__ inline float2 cmul(float2 a, float2 b) {
    return make_float2(a.x*b.x - a.y*b.y, a.x*b.y + a.y*b.x);
}

// F(u,v) = sum_{i<3,j<3} w[i,j] * exp(-2*pi*i*(u*i + v*j)/768), via LDS table
__device__ inline float2 evalF_t(int u, int v, const float* w9,
                                 const float2* __restrict__ tbl) {
    float fr = 0.f, fi = 0.f;
#pragma unroll
    for (int i = 0; i < 3; ++i) {
#pragma unroll
        for (int j = 0; j < 3; ++j) {
            int idx = u * i + v * j;          // <= 2302
            if (idx >= 2 * HP) idx -= 2 * HP;
            if (idx >= HP)     idx -= HP;
            float2 e = tbl[idx];
            float wv = w9[i * 3 + j];
            fr += wv * e.x;
            fi -= wv * e.y;
        }
    }
    return make_float2(fr, fi);
}

// One block per rfft column v. Builds gmf[.,v] in LDS, then
// P[a,v] = sum_u gmf[u,v] * exp(+2*pi*i*u*(a-K)/768)  for all 17 taps,
// parallelized 16 threads per tap.
__global__ __launch_bounds__(320) void filt_P_kernel(
        const float* __restrict__ w, float2* __restrict__ P) {
    __shared__ float2 tbl[HP];
    __shared__ float2 lg[HP];
    __shared__ float2 red[20][16];
    int v = blockIdx.x;
    int tid = threadIdx.x;

    float w9[9];
#pragma unroll
    for (int i = 0; i < 9; ++i) w9[i] = w[i];

    for (int m = tid; m < HP; m += 320) {
        float s, c;
        sincosf((float)m * TWO_PI_OVER_HP, &s, &c);
        tbl[m] = make_float2(c, s);
    }
    __syncthreads();

    int sv = (v == 0) ? 0 : (NV - v);   // reference's reverse+roll index
    for (int u = tid; u < HP; u += 320) {
        int su = (HP - u) % HP;
        float2 F1 = evalF_t(u,  v,  w9, tbl);
        float2 F2 = evalF_t(su, v,  w9, tbl);
        float2 F3 = evalF_t(u,  sv, w9, tbl);
        float2 F4 = evalF_t(su, sv, w9, tbl);
        float2 pr = cmul(cmul(F1, F2), cmul(F3, F4));
        float d = pr.x * pr.x + pr.y * pr.y;
        lg[u] = make_float2(pr.x / d, -pr.y / d);   // 1/prod
    }
    __syncthreads();

    int a   = tid >> 4;   // 0..19 (taps 0..16 valid)
    int sub = tid & 15;
    if (a < A) {
        int ap  = a - K;
        int apu = (ap < 0) ? ap + HP : ap;
        float Pr = 0.f, Pi = 0.f;
        for (int u = sub; u < HP; u += 16) {
            int idx = (u * apu) % HP;
            float2 e = tbl[idx];
            float2 g = lg[u];
            Pr += g.x * e.x - g.y * e.y;
            Pi += g.x * e.y + g.y * e.x;
        }
        red[a][sub] = make_float2(Pr, Pi);
    }
    __syncthreads();
    if (tid < A) {
        float Pr = 0.f, Pi = 0.f;
#pragma unroll
        for (int s2 = 0; s2 < 16; ++s2) { Pr += red[tid][s2].x; Pi += red[tid][s2].y; }
        P[tid * NV + v] = make_float2(Pr, Pi);
    }
}

// g[a,b] = (1/768^2) * sum_v w_v * Re(P[a,v] * exp(+2*pi*i*v*(b-K)/768))
__global__ __launch_bounds__(256) void filt_gk_kernel(
        const float2* __restrict__ P, float* __restrict__ gk) {
    __shared__ float2 tbl[HP];
    int tid = threadIdx.x;
    int id = blockIdx.x * 256 + tid;
    for (int m = tid; m < HP; m += 256) {
        float s, c;
        sincosf((float)m * TWO_PI_OVER_HP, &s, &c);
        tbl[m] = make_float2(c, s);
    }
    __syncthreads();
    if (id >= A * A) return;
    int ai = id / A;
    int bi = id - ai * A;
    int bp = bi - K;
    int bpu = (bp < 0) ? bp + HP : bp;
    float sum = 0.f;
    int idx = 0;
    for (int vv = 0; vv < NV; ++vv) {
        float wv = (vv == 0 || vv == NV - 1) ? 1.f : 2.f;
        float2 e = tbl[idx];
        float2 p = P[ai * NV + vv];
        sum += wv * (p.x * e.x - p.y * e.y);
        idx += bpu;
        if (idx >= HP) idx -= HP;
    }
    gk[id] = sum * (1.f / ((float)HP * (float)HP));
}

// Direct 17x17 convolution of zero-padded x into the 768x768 output grid.
// Block: (8,32) threads; tile 64x32 outputs; thread computes 8 cols x 1 row.
__global__ __launch_bounds__(256, 4) void deconv_kernel(
        const float* __restrict__ x, const float* __restrict__ gkg,
        float* __restrict__ out) {
    __shared__ __align__(16) float tile[LH * LWS];   // 48*84*4 = 16128 B
    __shared__ __align__(16) float gkr[A * GKS];     // flipped + padded taps

    int tx = threadIdx.x;   // 0..7
    int ty = threadIdx.y;   // 0..31
    int tid = ty * 8 + tx;
    int bx = blockIdx.x, by = blockIdx.y, bz = blockIdx.z;

    int ix0 = bx * TW - PADO;
    int iy0 = by * TH - PADO;
    int oy  = by * TH + ty;
    int ox0 = bx * TW + tx * 8;
    float4* outp = (float4*)(out + ((size_t)bz * HP + oy) * HP + ox0);

    bool active = (iy0 <= HIN - 1) && (iy0 + LH - 1 >= 0) &&
                  (ix0 <= WIN - 1) && (ix0 + LWL - 1 >= 0);
    if (!active) {
        outp[0] = make_float4(0.f, 0.f, 0.f, 0.f);
        outp[1] = make_float4(0.f, 0.f, 0.f, 0.f);
        return;
    }

    // stage flipped taps into LDS (broadcast-read later)
    for (int l = tid; l < A * GKS; l += 256) {
        int aa = l / GKS, bb = l - aa * GKS;
        gkr[l] = (bb < A) ? gkg[(2 * K - aa) * A + (2 * K - bb)] : 0.f;
    }

    // stage input tile, float4-granular (ix0 and boundaries are %4==0)
    const float* xb = x + (size_t)bz * HIN * WIN;
    for (int l = tid; l < LH * (LWL / 4); l += 256) {   // 48*20 = 960
        int r = l / 20, c4 = l - r * 20;
        int gy = iy0 + r;
        int gx = ix0 + c4 * 4;
        float4 val = make_float4(0.f, 0.f, 0.f, 0.f);
        if ((unsigned)gy < (unsigned)HIN && (unsigned)gx < (unsigned)WIN)
            val = *(const float4*)&xb[gy * WIN + gx];
        *(float4*)&tile[r * LWS + c4 * 4] = val;
    }
    __syncthreads();

    float acc[8];
#pragma unroll
    for (int c = 0; c < 8; ++c) acc[c] = 0.f;

#pragma unroll 1
    for (int aa = 0; aa < A; ++aa) {
        float rb[24];
        const float* rowp = &tile[(ty + aa) * LWS + tx * 8];
#pragma unroll
        for (int q = 0; q < 6; ++q)
            *(float4*)&rb[q * 4] = *(const float4*)&rowp[q * 4];
        const float* gp = &gkr[aa * GKS];
#pragma unroll
        for (int b4 = 0; b4 < 4; ++b4) {
            float4 g4 = *(const float4*)&gp[b4 * 4];
#pragma unroll
            for (int c = 0; c < 8; ++c) {
                acc[c] += g4.x * rb[b4 * 4 + 0 + c];
                acc[c] += g4.y * rb[b4 * 4 + 1 + c];
                acc[c] += g4.z * rb[b4 * 4 + 2 + c];
                acc[c] += g4.w * rb[b4 * 4 + 3 + c];
            }
        }
        float gs = gp[16];
#pragma unroll
        for (int c = 0; c < 8; ++c) acc[c] += gs * rb[16 + c];
    }
    outp[0] = make_float4(acc[0], acc[1], acc[2], acc[3]);
    outp[1] = make_float4(acc[4], acc[5], acc[6], acc[7]);
}

extern "C" void kernel_launch(void* const* d_in, const int* in_sizes, int n_in,
                              void* d_out, int out_size, void* d_ws, size_t ws_size,
                              hipStream_t stream) {
    const float* x = (const float*)d_in[0];   // (64, 512, 512) fp32
    const float* w = (const float*)d_in[1];   // (3, 3) fp32
    float* out = (float*)d_out;               // (64, 768, 768) fp32

    // workspace layout (floats): P = A*NV float2, then gk = A*A floats
    float2* P  = (float2*)d_ws;
    float*  gk = (float*)d_ws + (size_t)A * NV * 2;

    filt_P_kernel<<<dim3(NV), dim3(320), 0, stream>>>(w, P);
    filt_gk_kernel<<<dim3(2), dim3(256), 0, stream>>>(P, gk);
    deconv_kernel<<<dim3(HP / TW, HP / TH, 64), dim3(8, 32), 0, stream>>>(x, gk, out);
}

// Round 3
// 448.098 us; speedup vs baseline: 1.9766x; 1.1072x over previous
//
#include <hip/hip_runtime.h>

#define HP   768      // padded H (=W)
#define NV   385      // HP/2 + 1
#define HIN  512
#define WIN  512
#define K    8        // truncation radius of spatial inverse kernel
#define A    17       // 2K+1
#define PADO 136      // PAD + K = 128 + 8
#define TW   64       // output tile width
#define TH   64       // output tile height (2 rows per thread)
#define LH   80       // TH + 2K
#define LWL  80       // TW + 2K (logical tile width)
#define LWS  84       // padded LDS row stride (20*ty mod 32 spreads banks)
#define HROWS 40      // rows per parity half-tile
#define HSIZE (HROWS * LWS)   // 3360 floats per half-tile

#define TWO_PI_OVER_HP 0.008181230868723419f  // 2*pi/768

__device__ inline float2 cmul(float2 a, float2 b) {
    return make_float2(a.x*b.x - a.y*b.y, a.x*b.y + a.y*b.x);
}

// F(u,v) = sum_{i<3,j<3} w[i,j] * exp(-2*pi*i*(u*i + v*j)/768), via LDS table
__device__ inline float2 evalF_t(int u, int v, const float* w9,
                                 const float2* __restrict__ tbl) {
    float fr = 0.f, fi = 0.f;
#pragma unroll
    for (int i = 0; i < 3; ++i) {
#pragma unroll
        for (int j = 0; j < 3; ++j) {
            int idx = u * i + v * j;          // <= 2302
            if (idx >= 2 * HP) idx -= 2 * HP;
            if (idx >= HP)     idx -= HP;
            float2 e = tbl[idx];
            float wv = w9[i * 3 + j];
            fr += wv * e.x;
            fi -= wv * e.y;
        }
    }
    return make_float2(fr, fi);
}

// One block per rfft column v. Builds gmf[.,v] in LDS, then
// P[a,v] = sum_u gmf[u,v] * exp(+2*pi*i*u*(a-K)/768)  for all 17 taps,
// parallelized 16 threads per tap.
__global__ __launch_bounds__(320) void filt_P_kernel(
        const float* __restrict__ w, float2* __restrict__ P) {
    __shared__ float2 tbl[HP];
    __shared__ float2 lg[HP];
    __shared__ float2 red[20][16];
    int v = blockIdx.x;
    int tid = threadIdx.x;

    float w9[9];
#pragma unroll
    for (int i = 0; i < 9; ++i) w9[i] = w[i];

    for (int m = tid; m < HP; m += 320) {
        float s, c;
        sincosf((float)m * TWO_PI_OVER_HP, &s, &c);
        tbl[m] = make_float2(c, s);
    }
    __syncthreads();

    int sv = (v == 0) ? 0 : (NV - v);   // reference's reverse+roll index
    for (int u = tid; u < HP; u += 320) {
        int su = (HP - u) % HP;
        float2 F1 = evalF_t(u,  v,  w9, tbl);
        float2 F2 = evalF_t(su, v,  w9, tbl);
        float2 F3 = evalF_t(u,  sv, w9, tbl);
        float2 F4 = evalF_t(su, sv, w9, tbl);
        float2 pr = cmul(cmul(F1, F2), cmul(F3, F4));
        float d = pr.x * pr.x + pr.y * pr.y;
        lg[u] = make_float2(pr.x / d, -pr.y / d);   // 1/prod
    }
    __syncthreads();

    int a   = tid >> 4;   // 0..19 (taps 0..16 valid)
    int sub = tid & 15;
    if (a < A) {
        int ap  = a - K;
        int apu = (ap < 0) ? ap + HP : ap;
        float Pr = 0.f, Pi = 0.f;
        for (int u = sub; u < HP; u += 16) {
            int idx = (u * apu) % HP;
            float2 e = tbl[idx];
            float2 g = lg[u];
            Pr += g.x * e.x - g.y * e.y;
            Pi += g.x * e.y + g.y * e.x;
        }
        red[a][sub] = make_float2(Pr, Pi);
    }
    __syncthreads();
    if (tid < A) {
        float Pr = 0.f, Pi = 0.f;
#pragma unroll
        for (int s2 = 0; s2 < 16; ++s2) { Pr += red[tid][s2].x; Pi += red[tid][s2].y; }
        P[tid * NV + v] = make_float2(Pr, Pi);
    }
}

// g[a,b] = (1/768^2) * sum_v w_v * Re(P[a,v] * exp(+2*pi*i*v*(b-K)/768))
// Stored FLIPPED: gkf[(16-a)*17 + (16-b)] = g[a,b], so deconv reads ascending.
__global__ __launch_bounds__(256) void filt_gk_kernel(
        const float2* __restrict__ P, float* __restrict__ gkf) {
    __shared__ float2 tbl[HP];
    int tid = threadIdx.x;
    int id = blockIdx.x * 256 + tid;
    for (int m = tid; m < HP; m += 256) {
        float s, c;
        sincosf((float)m * TWO_PI_OVER_HP, &s, &c);
        tbl[m] = make_float2(c, s);
    }
    __syncthreads();
    if (id >= A * A) return;
    int ai = id / A;
    int bi = id - ai * A;
    int bp = bi - K;
    int bpu = (bp < 0) ? bp + HP : bp;
    float sum = 0.f;
    int idx = 0;
    for (int vv = 0; vv < NV; ++vv) {
        float wv = (vv == 0 || vv == NV - 1) ? 1.f : 2.f;
        float2 e = tbl[idx];
        float2 p = P[ai * NV + vv];
        sum += wv * (p.x * e.x - p.y * e.y);
        idx += bpu;
        if (idx >= HP) idx -= HP;
    }
    gkf[(2 * K - ai) * A + (2 * K - bi)] = sum * (1.f / ((float)HP * (float)HP));
}

// Direct 17x17 convolution of zero-padded x into the 768x768 output grid.
// Block (8,32); tile 64x64 outputs; thread computes 8 cols x 2 adjacent rows
// with a rolling register row-buffer (1 new LDS row per tap).
__global__ __launch_bounds__(256, 4) void deconv_kernel(
        const float* __restrict__ x, const float* __restrict__ gkf,
        float* __restrict__ out) {
    // parity-split tile: even tile-rows in [0], odd in [1] (bank spread)
    __shared__ __align__(16) float tile[2 * HSIZE];   // 26880 B

    const int tx = threadIdx.x;   // 0..7
    const int ty = threadIdx.y;   // 0..31
    const int tid = ty * 8 + tx;
    const int bx = blockIdx.x, by = blockIdx.y, bz = blockIdx.z;

    const int ix0 = bx * TW - PADO;
    const int iy0 = by * TH - PADO;
    const int oy0 = by * TH + ty * 2;
    const int ox0 = bx * TW + tx * 8;
    float* orow0 = out + ((size_t)bz * HP + oy0) * HP + ox0;
    float* orow1 = orow0 + HP;

    const bool active = (iy0 <= HIN - 1) && (iy0 + LH - 1 >= 0) &&
                        (ix0 <= WIN - 1) && (ix0 + LWL - 1 >= 0);
    if (!active) {
        float4 z = make_float4(0.f, 0.f, 0.f, 0.f);
        ((float4*)orow0)[0] = z; ((float4*)orow0)[1] = z;
        ((float4*)orow1)[0] = z; ((float4*)orow1)[1] = z;
        return;
    }

    // stage input tile (float4-granular; ix0 % 4 == 0 so no partial float4)
    const float* xb = x + (size_t)bz * (HIN * WIN);
    for (int l = tid; l < LH * (LWL / 4); l += 256) {   // 80*20 = 1600
        int r = l / 20, c4 = l - r * 20;
        int gy = iy0 + r;
        int gx = ix0 + c4 * 4;
        float4 val = make_float4(0.f, 0.f, 0.f, 0.f);
        if ((unsigned)gy < (unsigned)HIN && (unsigned)gx < (unsigned)WIN)
            val = *(const float4*)&xb[gy * WIN + gx];
        *(float4*)&tile[(r & 1) * HSIZE + (r >> 1) * LWS + c4 * 4] = val;
    }
    __syncthreads();

    const float* tE = tile;           // tile rows 0,2,4,...
    const float* tO = tile + HSIZE;   // tile rows 1,3,5,...

    float accA[8], accB[8];
#pragma unroll
    for (int c = 0; c < 8; ++c) { accA[c] = 0.f; accB[c] = 0.f; }
    float rbA[24], rbB[24];

    auto loadRow = [&](float* rb, const float* tb, int rowp) {
        const float* p = tb + rowp * LWS + tx * 8;
#pragma unroll
        for (int q = 0; q < 6; ++q)
            *(float4*)&rb[q * 4] = *(const float4*)&p[q * 4];
    };
    // gp is wave-uniform -> scalar loads; v_fmac with SGPR src0
    auto fmaPair = [&](const float* gp, const float* rx, const float* ry) {
#pragma unroll
        for (int bb = 0; bb < A; ++bb) {
            float g = gp[bb];
#pragma unroll
            for (int c = 0; c < 8; ++c) {
                accA[c] += g * rx[bb + c];
                accB[c] += g * ry[bb + c];
            }
        }
    };

    loadRow(rbA, tE, ty);                      // input tile-row 2ty
#pragma unroll 1
    for (int aa = 0; aa < 16; aa += 2) {
        int h = aa >> 1;
        loadRow(rbB, tO, ty + h);              // row 2ty+aa+1
        fmaPair(gkf + aa * A, rbA, rbB);       // tap aa
        loadRow(rbA, tE, ty + h + 1);          // row 2ty+aa+2
        fmaPair(gkf + (aa + 1) * A, rbB, rbA); // tap aa+1
    }
    loadRow(rbB, tO, ty + 8);                  // row 2ty+17
    fmaPair(gkf + 16 * A, rbA, rbB);           // tap 16

    ((float4*)orow0)[0] = make_float4(accA[0], accA[1], accA[2], accA[3]);
    ((float4*)orow0)[1] = make_float4(accA[4], accA[5], accA[6], accA[7]);
    ((float4*)orow1)[0] = make_float4(accB[0], accB[1], accB[2], accB[3]);
    ((float4*)orow1)[1] = make_float4(accB[4], accB[5], accB[6], accB[7]);
}

extern "C" void kernel_launch(void* const* d_in, const int* in_sizes, int n_in,
                              void* d_out, int out_size, void* d_ws, size_t ws_size,
                              hipStream_t stream) {
    const float* x = (const float*)d_in[0];   // (64, 512, 512) fp32
    const float* w = (const float*)d_in[1];   // (3, 3) fp32
    float* out = (float*)d_out;               // (64, 768, 768) fp32

    // workspace layout (floats): P = A*NV float2, then gkf = A*A floats
    float2* P   = (float2*)d_ws;
    float*  gkf = (float*)d_ws + (size_t)A * NV * 2;

    filt_P_kernel<<<dim3(NV), dim3(320), 0, stream>>>(w, P);
    filt_gk_kernel<<<dim3(2), dim3(256), 0, stream>>>(P, gkf);
    deconv_kernel<<<dim3(HP / TW, HP / TH, 64), dim3(8, 32), 0, stream>>>(x, gkf, out);
}